// Round 1
// baseline (47.327 us; speedup 1.0000x reference)
//
#include <hip/hip_runtime.h>

// MotionResidualBranch: the entire pipeline (V/A temporal diffs -> phi
// projections -> part-weighted sums -> WM -> depthwise conv3 -> pointwise
// -> LayerNorm) is LINEAR in 15 per-(b,t) scalars. We precompute folded
// tables on-device each launch (deterministic), then the main kernel is a
// 45-term FMA per output element + LayerNorm.

#define DD 256
#define KK 54
#define BB 8
#define TT 1024
#define NCOEF 15      // 3 parts x {v0, v1, a0, a1, w}
#define TS 16         // t-strip per block in main kernel

// ---------- P1: Mfold[i][d] = sum_e WM_w[d, p*256+e] * phi_i[e] ----------
__global__ __launch_bounds__(256) void p1_mfold(
    const float* __restrict__ phi_v_w, const float* __restrict__ phi_v_b,
    const float* __restrict__ phi_a_w, const float* __restrict__ phi_a_b,
    const float* __restrict__ gamma_v, const float* __restrict__ gamma_a,
    const float* __restrict__ WM_w, float* __restrict__ mfold)
{
    int i = blockIdx.x;          // 0..14
    int d = threadIdx.x;         // 0..255
    int p = i / 5, q = i - p * 5;
    const float gv = gamma_v[0], ga = gamma_a[0];
    const float* wrow = WM_w + (size_t)d * (3 * DD) + p * DD;
    float acc = 0.f;
    if (q == 4) {
        for (int e = 0; e < DD; ++e)
            acc += wrow[e] * (gv * phi_v_b[e] + ga * phi_a_b[e]);
    } else {
        const float* phi = (q < 2) ? phi_v_w : phi_a_w;
        int c = q & 1;
        for (int e = 0; e < DD; ++e)
            acc += wrow[e] * phi[e * 2 + c];
    }
    mfold[i * DD + d] = acc;
}

// ---------- P2: G[j][i][e], H[j][e], base[e] ----------
__global__ __launch_bounds__(256) void p2_tables(
    const float* __restrict__ mfold, const float* __restrict__ WM_b,
    const float* __restrict__ dw_w, const float* __restrict__ dw_b,
    const float* __restrict__ pw_w, const float* __restrict__ pw_b,
    float* __restrict__ Gt, float* __restrict__ Ht, float* __restrict__ baset)
{
    int o = blockIdx.x;          // 0..48
    int e = threadIdx.x;
    const float* prow = pw_w + (size_t)e * DD;
    float acc = 0.f;
    if (o < 45) {
        int j = o / 15, i = o - j * 15;
        for (int d = 0; d < DD; ++d)
            acc += prow[d] * dw_w[d * 3 + j] * mfold[i * DD + d];
        Gt[(j * NCOEF + i) * DD + e] = acc;
    } else if (o < 48) {
        int j = o - 45;
        for (int d = 0; d < DD; ++d)
            acc += prow[d] * dw_w[d * 3 + j] * WM_b[d];
        Ht[j * DD + e] = acc;
    } else {
        for (int d = 0; d < DD; ++d)
            acc += prow[d] * dw_b[d];
        baset[e] = acc + pw_b[e];
    }
}

// ---------- C: coefficients, one wave per (b,t) ----------
__global__ __launch_bounds__(256) void coef_kernel(
    const float* __restrict__ barX, const float* __restrict__ W,
    const float* __restrict__ gamma_v, const float* __restrict__ gamma_a,
    float* __restrict__ coef)
{
    int wave = threadIdx.x >> 6;
    int lane = threadIdx.x & 63;
    int bt = blockIdx.x * 4 + wave;      // 0..8191
    int t = bt & (TT - 1);

    __shared__ float lds[4][64][5];

    float w = 0.f, v0 = 0.f, v1 = 0.f, a0 = 0.f, a1 = 0.f;
    if (lane < KK) {
        w = W[(size_t)bt * KK + lane];
        const float* xp = barX + ((size_t)bt * KK + lane) * 2;
        float x0 = xp[0], x1 = xp[1];
        float xm0 = 0.f, xm1 = 0.f, xmm0 = 0.f, xmm1 = 0.f;
        if (t >= 1) { xm0 = xp[-KK * 2];     xm1 = xp[-KK * 2 + 1]; }
        if (t >= 2) { xmm0 = xp[-2 * KK * 2]; xmm1 = xp[-2 * KK * 2 + 1]; }
        v0 = x0 - xm0; v1 = x1 - xm1;
        float vm0 = (t >= 1) ? (xm0 - xmm0) : 0.f;
        float vm1 = (t >= 1) ? (xm1 - xmm1) : 0.f;
        a0 = v0 - vm0; a1 = v1 - vm1;
    }
    // wave-wide sum of W (lanes >= 54 contribute 0)
    float wsum = w;
#pragma unroll
    for (int m = 32; m; m >>= 1) wsum += __shfl_xor(wsum, m);
    float inv = 1.f / (wsum + 1e-6f);
    float wn = w * inv;

    lds[wave][lane][0] = wn * v0;
    lds[wave][lane][1] = wn * v1;
    lds[wave][lane][2] = wn * a0;
    lds[wave][lane][3] = wn * a1;
    lds[wave][lane][4] = wn;
    __syncthreads();

    if (lane < NCOEF) {
        int p = lane / 5, q = lane - p * 5;
        int k0 = (p == 0) ? 0  : (p == 1) ? 12 : 33;
        int k1 = (p == 0) ? 12 : (p == 1) ? 33 : 54;
        float acc = 0.f;
        for (int k = k0; k < k1; ++k) acc += lds[wave][k][q];
        if (q < 2)      acc *= gamma_v[0];
        else if (q < 4) acc *= gamma_a[0];
        coef[(size_t)bt * NCOEF + lane] = acc;
    }
}

// ---------- M: main — 45-FMA matvec + LayerNorm ----------
__global__ __launch_bounds__(256) void main_kernel(
    const float* __restrict__ coef, const float* __restrict__ Gt,
    const float* __restrict__ Ht, const float* __restrict__ baset,
    const float* __restrict__ ln_w, const float* __restrict__ ln_b,
    float* __restrict__ out)
{
    const int strips = TT / TS;
    int b  = blockIdx.x / strips;
    int t0 = (blockIdx.x - b * strips) * TS;
    int e  = threadIdx.x;
    int wave = e >> 6, lane = e & 63;

    // table registers (statically indexed — stays in VGPRs)
    float Gr[45];
#pragma unroll
    for (int ji = 0; ji < 45; ++ji) Gr[ji] = Gt[ji * DD + e];
    float H0 = Ht[0 * DD + e], H1 = Ht[1 * DD + e], H2 = Ht[2 * DD + e];
    float bs = baset[e];
    float lw = ln_w[e], lb = ln_b[e];

    __shared__ float cs[(TS + 2) * NCOEF];
    __shared__ float red[2][4][2];

    // stage coef rows t0-1 .. t0+TS (invalid rows -> 0)
    for (int idx = threadIdx.x; idx < (TS + 2) * NCOEF; idx += 256) {
        int r = idx / NCOEF, i = idx - r * NCOEF;
        int gt = t0 - 1 + r;
        float v = 0.f;
        if (gt >= 0 && gt < TT) v = coef[((size_t)b * TT + gt) * NCOEF + i];
        cs[idx] = v;
    }
    __syncthreads();

    for (int tl = 0; tl < TS; ++tl) {
        int t = t0 + tl;
        float acc = bs + H1;
        if (t > 0)      acc += H0;
        if (t < TT - 1) acc += H2;
#pragma unroll
        for (int j = 0; j < 3; ++j)
#pragma unroll
            for (int i = 0; i < NCOEF; ++i)
                acc += cs[(tl + j) * NCOEF + i] * Gr[j * NCOEF + i];

        // LayerNorm: block reduce (sum, sumsq)
        float s = acc, ss = acc * acc;
#pragma unroll
        for (int m = 32; m; m >>= 1) {
            s  += __shfl_xor(s, m);
            ss += __shfl_xor(ss, m);
        }
        int par = tl & 1;
        if (lane == 0) { red[par][wave][0] = s; red[par][wave][1] = ss; }
        __syncthreads();
        float fs  = red[par][0][0] + red[par][1][0] + red[par][2][0] + red[par][3][0];
        float fss = red[par][0][1] + red[par][1][1] + red[par][2][1] + red[par][3][1];
        float mu  = fs * (1.f / DD);
        float var = fss * (1.f / DD) - mu * mu;
        float rs  = rsqrtf(var + 1e-5f);
        out[((size_t)b * TT + t) * DD + e] = (acc - mu) * rs * lw + lb;
    }
}

extern "C" void kernel_launch(void* const* d_in, const int* in_sizes, int n_in,
                              void* d_out, int out_size, void* d_ws, size_t ws_size,
                              hipStream_t stream) {
    const float* barX    = (const float*)d_in[0];
    const float* W       = (const float*)d_in[1];
    const float* phi_v_w = (const float*)d_in[2];
    const float* phi_v_b = (const float*)d_in[3];
    const float* phi_a_w = (const float*)d_in[4];
    const float* phi_a_b = (const float*)d_in[5];
    const float* gamma_v = (const float*)d_in[6];
    const float* gamma_a = (const float*)d_in[7];
    const float* WM_w    = (const float*)d_in[8];
    const float* WM_b    = (const float*)d_in[9];
    const float* dw_w    = (const float*)d_in[10];
    const float* dw_b    = (const float*)d_in[11];
    const float* pw_w    = (const float*)d_in[12];
    const float* pw_b    = (const float*)d_in[13];
    const float* ln_w    = (const float*)d_in[14];
    const float* ln_b    = (const float*)d_in[15];
    float* out = (float*)d_out;

    // workspace layout (floats)
    float* ws    = (float*)d_ws;
    float* mfold = ws;                 // 15*256   = 3840
    float* Gt    = ws + 3840;          // 45*256   = 11520
    float* Ht    = ws + 15360;         // 3*256    = 768
    float* baset = ws + 16128;         // 256
    float* coef  = ws + 16384;         // 8192*15  = 122880
    // total 139264 floats = 557056 B

    hipLaunchKernelGGL(p1_mfold, dim3(15), dim3(256), 0, stream,
                       phi_v_w, phi_v_b, phi_a_w, phi_a_b, gamma_v, gamma_a,
                       WM_w, mfold);
    hipLaunchKernelGGL(p2_tables, dim3(49), dim3(256), 0, stream,
                       mfold, WM_b, dw_w, dw_b, pw_w, pw_b, Gt, Ht, baset);
    hipLaunchKernelGGL(coef_kernel, dim3(BB * TT / 4), dim3(256), 0, stream,
                       barX, W, gamma_v, gamma_a, coef);
    hipLaunchKernelGGL(main_kernel, dim3(BB * (TT / TS)), dim3(256), 0, stream,
                       coef, Gt, Ht, baset, ln_w, ln_b, out);
}